// Round 23
// baseline (155.099 us; speedup 1.0000x reference)
//
#include <hip/hip_runtime.h>
#include <cstdint>
#include <cstddef>

#define BB 32
#define GG 50
#define CC 80
#define AA 8400
#define PCH (5 + CC)   // pred_output channels = 85
#define NLB ((BB * AA + 255) / 256)   // k_loss blocks = 1050
#define FGBIT 63       // fg0 folded into amask bit 63 (g uses bits 0..49)
#define SENTC 3.3e38f  // cost sentinel (> any real cost)
#define SENTI 0x7fffffff

__device__ __forceinline__ float logsig_fast(float x) {
    float e = __expf(-fabsf(x));
    return fminf(x, 0.f) - __logf(1.f + e);
}
__device__ __forceinline__ float softplusf(float x) {
    return fmaxf(x, 0.f) + log1pf(expf(-fabsf(x)));
}

// ---- shared value functions (MUST be identical everywhere) ----
__device__ __forceinline__ float pair_iou(float px, float py, float pw, float ph,
                                          float gx, float gy, float gw, float gh) {
    float tlx = fmaxf(gx - gw * 0.5f, px - pw * 0.5f);
    float tly = fmaxf(gy - gh * 0.5f, py - ph * 0.5f);
    float brx = fminf(gx + gw * 0.5f, px + pw * 0.5f);
    float bry = fminf(gy + gh * 0.5f, py + ph * 0.5f);
    float en = (tlx < brx && tly < bry) ? 1.f : 0.f;
    float ai = (brx - tlx) * (bry - tly) * en;
    return ai / (gw * gh + pw * ph - ai + 1e-16f);
}
__device__ __forceinline__ float cost_val(float x /*cls logit*/, float lo /*logsig(obj)*/,
                                          float sn /*s_neg*/, float v /*masked iou*/,
                                          bool ac, bool f0, bool valid) {
    float lq = 0.5f * (logsig_fast(x) + lo);
    float q = fminf(fmaxf(__expf(lq), 1e-7f), 1.f - 1e-7f);
    float cst = -__logf(q) + __logf(1.f - q) - sn;
    cst -= 3.0f * __logf(v + 1e-8f);
    cst += 100000.0f * (ac ? 0.f : 1.f);
    cst += 1000000000.0f * ((!f0 || !valid) ? 1.f : 0.f);
    return cst;
}

// ---------------- K1: geometry + fg0 compaction (runs FIRST; compacts pred box) ----
__global__ void k_geom(const float* __restrict__ labels, const float* __restrict__ xs,
                       const float* __restrict__ ys, const float* __restrict__ ss,
                       const float* __restrict__ pred,
                       unsigned long long* __restrict__ amask,
                       int* __restrict__ clist, unsigned long long* __restrict__ camask,
                       float4* __restrict__ cpbox, int* __restrict__ ccnt) {
    int b = blockIdx.y;
    int a = blockIdx.x * blockDim.x + threadIdx.x;
    __shared__ float lab[GG * 5];
    __shared__ int lv[GG];
    for (int t = threadIdx.x; t < GG * 5; t += blockDim.x) lab[t] = labels[b * GG * 5 + t];
    __syncthreads();
    if (threadIdx.x < GG) {
        const float* r = lab + threadIdx.x * 5;
        lv[threadIdx.x] = ((r[0] + r[1] + r[2] + r[3] + r[4]) > 0.f) ? 1 : 0;
    }
    __syncthreads();
    if (a >= AA) return;
    float s = ss[a];
    float xc = (xs[a] + 0.5f) * s;
    float yc = (ys[a] + 0.5f) * s;
    unsigned long long m = 0;
    int any = 0;
    for (int g = 0; g < GG; g++) {
        if (!lv[g]) continue;
        const float* r = lab + g * 5;
        float gx = r[1], gy = r[2], gw = r[3], gh = r[4];
        float d1 = xc - (gx - gw * 0.5f);
        float d2 = (gx + gw * 0.5f) - xc;
        float d3 = yc - (gy - gh * 0.5f);
        float d4 = (gy + gh * 0.5f) - yc;
        bool ib = fminf(fminf(d1, d2), fminf(d3, d4)) > 0.f;
        float cr = 2.5f * s;
        float e1 = xc - (gx - cr);
        float e2 = (gx + cr) - xc;
        float e3 = yc - (gy - cr);
        float e4 = (gy + cr) - yc;
        bool ic = fminf(fminf(e1, e2), fminf(e3, e4)) > 0.f;
        if (ib || ic) any = 1;
        if (ib && ic) m |= 1ull << g;
    }
    if (any) m |= 1ull << FGBIT;
    amask[b * AA + a] = m;
    int lane = threadIdx.x & 63;
    unsigned long long act = __ballot(m != 0);
    if (act) {
        int leader = __ffsll(act) - 1;
        int base = 0;
        if (lane == leader) base = atomicAdd(&ccnt[b], __popcll(act));
        base = __shfl(base, leader);
        if (m != 0) {
            int off = __popcll(act & ((1ull << lane) - 1ull));
            int pos = b * AA + base + off;
            clist[pos] = a;
            camask[pos] = m;
            const float* p = pred + (size_t)(b * AA + a) * PCH;
            cpbox[pos] = make_float4(p[0], p[1], p[2], p[3]);
        }
    }
}

// ---------------- K2: per-anchor precompute, fg0-COMPACTED anchors only ----------
__global__ __launch_bounds__(256)
void k_pre_fg(const float* __restrict__ obj, const float* __restrict__ cls,
              const int* __restrict__ clist, const int* __restrict__ ccnt,
              float2* __restrict__ clsn, float2* __restrict__ lsn,
              float* __restrict__ sps) {
    int b = blockIdx.y;
    int cnt = ccnt[b];
    int t = blockIdx.x * blockDim.x + threadIdx.x;
    int p = t >> 2;                    // compacted position
    int sub = t & 3;
    if (p >= cnt) return;
    int pos = b * AA + p;
    int a = clist[pos];
    int ia = b * AA + a;
    float lo = logsig_fast(obj[ia]);
    float K = __expf(0.5f * lo);
    const float4* c4 = (const float4*)(cls + (size_t)ia * CC);
    float smax = 0.f, psp = 1.f, p1 = 1.f, p2 = 1.f;
#pragma unroll
    for (int j = 0; j < 5; j++) {
        float4 v = c4[sub + 4 * j];
        float xs4[4] = {v.x, v.y, v.z, v.w};
        float pg = 1.f;
#pragma unroll
        for (int u = 0; u < 4; u++) {
            float x = xs4[u];
            float th = __expf(-0.5f * fabsf(x));
            float t2 = th * th;
            smax += fmaxf(x, 0.f);
            psp *= (1.f + t2);
            float qq = K * (x < 0.f ? th : 1.f) * rsqrtf(1.f + t2);
            qq = fminf(fmaxf(qq, 1e-7f), 1.f - 1e-7f);
            pg *= (1.f - qq);
        }
        if (j < 2) p1 *= pg; else p2 *= pg;
    }
    float sp = smax + __logf(psp);
    float sn = __logf(p1) + __logf(p2);
    sp += __shfl_xor(sp, 1); sn += __shfl_xor(sn, 1);
    sp += __shfl_xor(sp, 2); sn += __shfl_xor(sn, 2);
    if (sub == 0) {
        clsn[pos] = make_float2(lo, sn);
        lsn[ia] = make_float2(lo, sn);
        sps[ia] = sp;
    }
}

// ---------------- K3a: per (b,g,half) partial top-10s over compacted arrays --------
__global__ __launch_bounds__(256, 4)
void k_assign1(const float* __restrict__ cls,
               const unsigned long long* __restrict__ camask,
               const float4* __restrict__ cpbox, const float2* __restrict__ clsn,
               const int* __restrict__ clist, const int* __restrict__ ccnt,
               const float* __restrict__ labels,
               float* __restrict__ giou, float* __restrict__ gcost,
               int* __restrict__ gidx, int* __restrict__ gnac) {
    int w = blockIdx.x;              // b*GG + g
    int half = blockIdx.y;           // 0 or 1
    int b = w / GG, g = w % GG;
    const float* r = labels + (size_t)w * 5;
    float gcls = r[0], gx = r[1], gy = r[2], gw = r[3], gh = r[4];
    if (!((gcls + gx + gy + gw + gh) > 0.f)) return;  // invalid gt
    int gtc = (int)gcls;
    int tid = threadIdx.x;
    int lane = tid & 63;
    int wv = tid >> 6;               // 4 waves
    int cnt = ccnt[b];
    int hmid = (cnt + 1) >> 1;
    int hstart = half ? hmid : 0;
    int hend = half ? cnt : hmid;

    float ivl[10];
    float cvl[10];
    int   cil[10];
#pragma unroll
    for (int t = 0; t < 10; t++) { ivl[t] = 0.f; cvl[t] = SENTC; cil[t] = SENTI; }
    int nlc = 0;

    for (int i0 = hstart + wv * 64 + lane; i0 < hend; i0 += 256) {
        int pos = b * AA + i0;
        unsigned long long am = camask[pos];
        float4 pb = cpbox[pos];
        bool ac = (am >> g) & 1ull;
        nlc += ac ? 1 : 0;
        float v = pair_iou(pb.x, pb.y, pb.z, pb.w, gx, gy, gw, gh);
        if (v > ivl[9]) {
            float mv = v;
#pragma unroll
            for (int t = 0; t < 10; t++)
                if (mv > ivl[t]) { float tmp = ivl[t]; ivl[t] = mv; mv = tmp; }
        }
        if (ac) {
            int a = clist[pos];
            float2 ls = clsn[pos];
            float c = cost_val(cls[((size_t)b * AA + a) * CC + gtc], ls.x, ls.y, v,
                               true, true, true);
            int id = a;
            if (c < cvl[9] || (c == cvl[9] && id < cil[9])) {
#pragma unroll
                for (int t = 0; t < 10; t++) {
                    bool sw = (c < cvl[t]) || (c == cvl[t] && id < cil[t]);
                    if (sw) {
                        float tf = cvl[t]; cvl[t] = c; c = tf;
                        int ti = cil[t]; cil[t] = id; id = ti;
                    }
                }
            }
        }
    }

    __shared__ float IV[4][10];
    __shared__ float CV[4][10];
    __shared__ int CI[4][10];
    __shared__ int NAC[4];

    {
        int s = nlc;
#pragma unroll
        for (int off = 1; off < 64; off <<= 1) s += __shfl_xor(s, off);
        if (lane == 0) NAC[wv] = s;
    }

    // wave iou top-10: 10 extraction rounds
    for (int rr = 0; rr < 10; rr++) {
        float bv = ivl[0];
        int bl = lane;
#pragma unroll
        for (int off = 1; off < 64; off <<= 1) {
            float ov = __shfl_xor(bv, off);
            int ol = __shfl_xor(bl, off);
            if (ov > bv || (ov == bv && ol < bl)) { bv = ov; bl = ol; }
        }
        if (lane == 0) IV[wv][rr] = bv;
        if (lane == bl) {
#pragma unroll
            for (int t = 0; t < 9; t++) ivl[t] = ivl[t + 1];
            ivl[9] = 0.f;
        }
    }
    // wave cost top-10: 10 extraction rounds
    for (int rr = 0; rr < 10; rr++) {
        float bc = cvl[0];
        int bi = cil[0];
        int bl = lane;
#pragma unroll
        for (int off = 1; off < 64; off <<= 1) {
            float oc = __shfl_xor(bc, off);
            int oi = __shfl_xor(bi, off);
            int ol = __shfl_xor(bl, off);
            bool tk = (oc < bc) || (oc == bc && (oi < bi || (oi == bi && ol < bl)));
            if (tk) { bc = oc; bi = oi; bl = ol; }
        }
        if (lane == 0) { CV[wv][rr] = bc; CI[wv][rr] = bi; }
        if (lane == bl) {
#pragma unroll
            for (int t = 0; t < 9; t++) { cvl[t] = cvl[t + 1]; cil[t] = cil[t + 1]; }
            cvl[9] = SENTC; cil[9] = SENTI;
        }
    }
    __syncthreads();

    if (tid == 0) {
        size_t obase = ((size_t)w * 2 + half) * 10;
        int h[4] = {0, 0, 0, 0};
        for (int j = 0; j < 10; j++) {      // 4-way descending merge of iou lists
            float bv = -1.f; int bc = 0;
#pragma unroll
            for (int c2 = 0; c2 < 4; c2++)
                if (h[c2] < 10 && IV[c2][h[c2]] > bv) { bv = IV[c2][h[c2]]; bc = c2; }
            giou[obase + j] = bv;
            h[bc]++;
        }
        h[0] = h[1] = h[2] = h[3] = 0;
        for (int j = 0; j < 10; j++) {      // 4-way lex-ascending merge of cost lists
            float bv = SENTC; int bix = SENTI; int bc = 0;
#pragma unroll
            for (int c2 = 0; c2 < 4; c2++) {
                if (h[c2] < 10) {
                    float av = CV[c2][h[c2]]; int ax = CI[c2][h[c2]];
                    if (av < bv || (av == bv && ax < bix)) { bv = av; bix = ax; bc = c2; }
                }
            }
            gcost[obase + j] = bv;
            gidx[obase + j] = bix;
            h[bc]++;
        }
        gnac[w * 2 + half] = NAC[0] + NAC[1] + NAC[2] + NAC[3];
    }
}

// ---------------- K3b: merge halves, dyn_k, select, atomicOr (1 wave per (b,g)) ----
__global__ __launch_bounds__(64)
void k_assign2(const float* __restrict__ labels,
               const float* __restrict__ giou, const float* __restrict__ gcost,
               const int* __restrict__ gidx, const int* __restrict__ gnac,
               const float* __restrict__ pred, const float2* __restrict__ lsn,
               const float* __restrict__ cls,
               const unsigned long long* __restrict__ amask,
               unsigned long long* __restrict__ mmask) {
    int w = blockIdx.x;
    int b = w / GG, g = w % GG;
    const float* r = labels + (size_t)w * 5;
    float gcls = r[0], gx = r[1], gy = r[2], gw = r[3], gh = r[4];
    if (!((gcls + gx + gy + gw + gh) > 0.f)) return;
    int gtc = (int)gcls;
    int lane = threadIdx.x;

    __shared__ int s_k, s_n0;
    __shared__ int sel[10];

    if (lane == 0) {
        size_t o0 = (size_t)w * 2 * 10, o1 = o0 + 10;
        int h0 = 0, h1 = 0;
        float ssum = 0.f;
        for (int j = 0; j < 10; j++) {      // 2-way descending merge, take 10
            float a0 = (h0 < 10) ? giou[o0 + h0] : -1.f;
            float a1 = (h1 < 10) ? giou[o1 + h1] : -1.f;
            if (a0 >= a1) { ssum += a0; h0++; }
            else          { ssum += a1; h1++; }
        }
        int k = (int)ssum;
        if (k < 1) k = 1;
        s_k = k;
        s_n0 = gnac[w * 2] + gnac[w * 2 + 1];
        if (s_n0 >= k) {
            h0 = h1 = 0;
            for (int j = 0; j < k; j++) {   // 2-way lex-ascending merge, take k
                float a0 = (h0 < 10) ? gcost[o0 + h0] : SENTC;
                int x0 = (h0 < 10) ? gidx[o0 + h0] : SENTI;
                float a1 = (h1 < 10) ? gcost[o1 + h1] : SENTC;
                int x1 = (h1 < 10) ? gidx[o1 + h1] : SENTI;
                bool t0 = (a0 < a1) || (a0 == a1 && x0 < x1);
                if (t0) { sel[j] = x0; h0++; }
                else    { sel[j] = x1; h1++; }
            }
        }
    }
    __syncthreads();
    int k = s_k;

    if (s_n0 < k) {
        // ---- rare fallback: single-wave full-cost rescan over ALL anchors ----
        float cvl[10];
        int cil[10];
#pragma unroll
        for (int t = 0; t < 10; t++) { cvl[t] = SENTC; cil[t] = SENTI; }
        for (int a = lane; a < AA; a += 64) {
            int ia = b * AA + a;
            unsigned long long am = amask[ia];
            bool f0 = (am >> FGBIT) & 1ull;
            bool ac = (am >> g) & 1ull;
            float v = 0.f;
            if (f0) {
                const float* p = pred + (size_t)ia * PCH;
                v = pair_iou(p[0], p[1], p[2], p[3], gx, gy, gw, gh);
            }
            float x = cls[(size_t)ia * CC + gtc];
            float2 ls = lsn[ia];
            float c = cost_val(x, ls.x, ls.y, v, ac, f0, true);
            int id = a;
            if (c < cvl[9] || (c == cvl[9] && id < cil[9])) {
#pragma unroll
                for (int t = 0; t < 10; t++) {
                    bool sw = (c < cvl[t]) || (c == cvl[t] && id < cil[t]);
                    if (sw) {
                        float tf = cvl[t]; cvl[t] = c; c = tf;
                        int ti = cil[t]; cil[t] = id; id = ti;
                    }
                }
            }
        }
        for (int rr = 0; rr < k; rr++) {
            float bc = cvl[0];
            int bi = cil[0];
            int bl = lane;
#pragma unroll
            for (int off = 1; off < 64; off <<= 1) {
                float oc = __shfl_xor(bc, off);
                int oi = __shfl_xor(bi, off);
                int ol = __shfl_xor(bl, off);
                bool tk = (oc < bc) || (oc == bc && (oi < bi || (oi == bi && ol < bl)));
                if (tk) { bc = oc; bi = oi; bl = ol; }
            }
            if (lane == 0) sel[rr] = bi;
            if (lane == bl) {
#pragma unroll
                for (int t = 0; t < 9; t++) { cvl[t] = cvl[t + 1]; cil[t] = cil[t + 1]; }
                cvl[9] = SENTC; cil[9] = SENTI;
            }
        }
        __syncthreads();
    }

    if (lane < k) {
        atomicOr(&mmask[(size_t)b * AA + sel[lane]], 1ull << g);
    }
}

// ---------------- K4: loss partials; labels in LDS; box from pred (masked) ----
__global__ void k_loss(const float* __restrict__ pred, const float* __restrict__ obj,
                       const float* __restrict__ cls, const float* __restrict__ labels,
                       const float2* __restrict__ lsn,
                       const unsigned long long* __restrict__ amask,
                       const unsigned long long* __restrict__ mmask,
                       const float* __restrict__ sps, float* __restrict__ partial) {
    int i = blockIdx.x * blockDim.x + threadIdx.x;
    int i_first = blockIdx.x * blockDim.x;
    int i_last = min(i_first + (int)blockDim.x - 1, BB * AA - 1);
    int b0 = i_first / AA, b1 = i_last / AA;
    __shared__ float lab[2][GG * 5];
    for (int t = threadIdx.x; t < GG * 5; t += blockDim.x) {
        lab[0][t] = labels[(size_t)b0 * GG * 5 + t];
        lab[1][t] = labels[(size_t)b1 * GG * 5 + t];
    }
    __syncthreads();

    float li = 0.f, lo = 0.f, lc = 0.f, nf = 0.f;
    if (i < BB * AA) {
        int b = i / AA, a = i % AA;
        const float* lb = lab[(b == b0) ? 0 : 1];
        unsigned long long m = mmask[i];
        int cnt = __popcll(m);
        bool fg = (m != 0);
        int mg = 0;
        float4 pb = make_float4(0.f, 0.f, 0.f, 0.f);
        if (fg) {
            const float* p = pred + (size_t)i * PCH;
            pb = make_float4(p[0], p[1], p[2], p[3]);
        }
        unsigned long long am = amask[i];
        bool f0 = (am >> FGBIT) & 1ull;
        if (cnt > 1) {
            float2 ls = lsn[i];
            float bv = 3.4e38f;
            for (int g = 0; g < GG; g++) {
                const float* r = lb + g * 5;
                float gcls = r[0], gx = r[1], gy = r[2], gw = r[3], gh = r[4];
                bool valid = (gcls + gx + gy + gw + gh) > 0.f;
                int gtc = (int)gcls;
                float raw = pair_iou(pb.x, pb.y, pb.z, pb.w, gx, gy, gw, gh);
                float v = raw * (f0 ? 1.f : 0.f) * (valid ? 1.f : 0.f);
                float x = cls[(size_t)i * CC + gtc];
                bool ac = (am >> g) & 1ull;
                float cst = cost_val(x, ls.x, ls.y, v, ac, f0, valid);
                if (cst < bv) { bv = cst; mg = g; }
            }
        } else if (cnt == 1) {
            mg = __ffsll((unsigned long long)m) - 1;
        }
        float o = obj[i];
        lo = softplusf(o) - (fg ? o : 0.f);
        if (fg) {
            const float* r = lb + mg * 5;
            float gcls = r[0], gx = r[1], gy = r[2], gw = r[3], gh = r[4];
            bool valid = (gcls + gx + gy + gw + gh) > 0.f;
            int gtc = (int)gcls;
            float piou = pair_iou(pb.x, pb.y, pb.z, pb.w, gx, gy, gw, gh)
                         * (f0 ? 1.f : 0.f) * (valid ? 1.f : 0.f);
            float tlx = fmaxf(pb.x - pb.z * 0.5f, gx - gw * 0.5f);
            float tly = fmaxf(pb.y - pb.w * 0.5f, gy - gh * 0.5f);
            float brx = fminf(pb.x + pb.z * 0.5f, gx + gw * 0.5f);
            float bry = fminf(pb.y + pb.w * 0.5f, gy + gh * 0.5f);
            float en = (tlx < brx && tly < bry) ? 1.f : 0.f;
            float ai = (brx - tlx) * (bry - tly) * en;
            float u = pb.z * pb.w + gw * gh - ai;
            float v2 = ai / (u + 1e-16f);
            li = 1.f - v2 * v2;
            lc = sps[i] - cls[(size_t)i * CC + gtc] * piou;
            nf = 1.f;
        }
    }
    for (int off = 32; off; off >>= 1) {
        li += __shfl_down(li, off);
        lo += __shfl_down(lo, off);
        lc += __shfl_down(lc, off);
        nf += __shfl_down(nf, off);
    }
    __shared__ float red[4][4];
    int wid = threadIdx.x >> 6;
    if ((threadIdx.x & 63) == 0) {
        red[wid][0] = li; red[wid][1] = lo; red[wid][2] = lc; red[wid][3] = nf;
    }
    __syncthreads();
    if (threadIdx.x == 0) {
        float s0 = 0.f, s1 = 0.f, s2 = 0.f, s3 = 0.f;
#pragma unroll
        for (int t = 0; t < 4; t++) {
            s0 += red[t][0]; s1 += red[t][1]; s2 += red[t][2]; s3 += red[t][3];
        }
        ((float4*)partial)[blockIdx.x] = make_float4(s0, s1, s2, s3);
    }
}

// ---------------- K5: reduce partials, finalize ----------------
__global__ void k_final(const float* __restrict__ partial, float* __restrict__ out) {
    int tid = threadIdx.x;
    float s0 = 0.f, s1 = 0.f, s2 = 0.f, s3 = 0.f;
    const float4* pb = (const float4*)partial;
    for (int i = tid; i < NLB; i += 256) {
        float4 v = pb[i];
        s0 += v.x; s1 += v.y; s2 += v.z; s3 += v.w;
    }
    for (int off = 32; off; off >>= 1) {
        s0 += __shfl_down(s0, off);
        s1 += __shfl_down(s1, off);
        s2 += __shfl_down(s2, off);
        s3 += __shfl_down(s3, off);
    }
    __shared__ float red[4][4];
    int wid = tid >> 6;
    if ((tid & 63) == 0) {
        red[wid][0] = s0; red[wid][1] = s1; red[wid][2] = s2; red[wid][3] = s3;
    }
    __syncthreads();
    if (tid == 0) {
        float li = 0.f, lo = 0.f, lc = 0.f, nf = 0.f;
#pragma unroll
        for (int t = 0; t < 4; t++) {
            li += red[t][0]; lo += red[t][1]; lc += red[t][2]; nf += red[t][3];
        }
        nf = fmaxf(nf, 1.f);
        out[0] = (5.f * li + lo + lc) / nf;
    }
}

extern "C" void kernel_launch(void* const* d_in, const int* in_sizes, int n_in,
                              void* d_out, int out_size, void* d_ws, size_t ws_size,
                              hipStream_t stream) {
    const float* pred = (const float*)d_in[0];   // (B,A,85)
    const float* obj  = (const float*)d_in[1];   // (B,A,1)
    const float* cls  = (const float*)d_in[2];   // (B,A,80)
    const float* lab  = (const float*)d_in[3];   // (B,G,5)
    const float* xs   = (const float*)d_in[4];   // (A,)
    const float* ys   = (const float*)d_in[5];   // (A,)
    const float* ss   = (const float*)d_in[6];   // (A,)
    float* out = (float*)d_out;

    const size_t BA = (size_t)BB * AA;
    const size_t WH = (size_t)BB * GG * 2;       // (b,g,half) entries

    float4* cpbox = (float4*)d_ws;                 // BA f32x4 (compacted)
    float2* lsn   = (float2*)(cpbox + BA);         // BA f32x2 (scattered, fg0 only)
    float2* clsn  = lsn + BA;                      // BA f32x2 (compacted)
    unsigned long long* amask  = (unsigned long long*)(clsn + BA);  // BA u64
    unsigned long long* camask = amask + BA;       // BA u64 (compacted)
    unsigned long long* mmask  = camask + BA;      // BA u64
    float* sps = (float*)(mmask + BA);             // BA f32 (scattered, fg0 only)
    float* partial = sps + BA;                     // NLB*4 f32
    int* clist = (int*)(partial + (size_t)NLB * 4); // BA i32
    int* ccnt  = clist + BA;                        // BB i32
    float* giou = (float*)(ccnt + BB);              // WH*10 f32
    float* gcost = giou + WH * 10;                  // WH*10 f32
    int* gidx = (int*)(gcost + WH * 10);            // WH*10 i32
    int* gnac = gidx + WH * 10;                     // WH i32

    hipMemsetAsync(mmask, 0, BA * sizeof(unsigned long long), stream);
    hipMemsetAsync(ccnt, 0, BB * sizeof(int), stream);

    dim3 blk(256);
    // K1: geometry + compaction
    k_geom<<<dim3((AA + 255) / 256, BB), blk, 0, stream>>>(lab, xs, ys, ss, pred,
                                                           amask, clist, camask, cpbox,
                                                           ccnt);
    // K2: precompute only for compacted fg0 anchors
    k_pre_fg<<<dim3((AA * 4 + 255) / 256, BB), blk, 0, stream>>>(obj, cls, clist, ccnt,
                                                                 clsn, lsn, sps);
    // K3a: per (b,g,half) partial top-10s
    k_assign1<<<dim3(BB * GG, 2), blk, 0, stream>>>(cls, camask, cpbox, clsn, clist,
                                                    ccnt, lab, giou, gcost, gidx, gnac);
    // K3b: merge halves + dyn_k + select
    k_assign2<<<dim3(BB * GG), dim3(64), 0, stream>>>(lab, giou, gcost, gidx, gnac,
                                                      pred, lsn, cls, amask, mmask);
    // K4: loss partials
    k_loss<<<dim3(NLB), blk, 0, stream>>>(pred, obj, cls, lab, lsn, amask,
                                          mmask, sps, partial);
    // K5
    k_final<<<1, blk, 0, stream>>>(partial, out);
}

// Round 24
// 144.957 us; speedup vs baseline: 1.0700x; 1.0700x over previous
//
#include <hip/hip_runtime.h>
#include <cstdint>
#include <cstddef>

#define BB 32
#define GG 50
#define CC 80
#define AA 8400
#define PCH (5 + CC)   // pred_output channels = 85
#define NLB ((BB * AA + 255) / 256)   // k_loss blocks = 1050
#define FGBIT 63       // fg0 folded into amask bit 63 (g uses bits 0..49)
#define SENTC 3.3e38f  // cost sentinel (> any real cost)
#define SENTI 0x7fffffff

__device__ __forceinline__ float logsig_fast(float x) {
    float e = __expf(-fabsf(x));
    return fminf(x, 0.f) - __logf(1.f + e);
}
__device__ __forceinline__ float softplusf(float x) {
    return fmaxf(x, 0.f) + log1pf(expf(-fabsf(x)));
}

// ---- shared value functions (MUST be identical everywhere) ----
__device__ __forceinline__ float pair_iou(float px, float py, float pw, float ph,
                                          float gx, float gy, float gw, float gh) {
    float tlx = fmaxf(gx - gw * 0.5f, px - pw * 0.5f);
    float tly = fmaxf(gy - gh * 0.5f, py - ph * 0.5f);
    float brx = fminf(gx + gw * 0.5f, px + pw * 0.5f);
    float bry = fminf(gy + gh * 0.5f, py + ph * 0.5f);
    float en = (tlx < brx && tly < bry) ? 1.f : 0.f;
    float ai = (brx - tlx) * (bry - tly) * en;
    return ai / (gw * gh + pw * ph - ai + 1e-16f);
}
__device__ __forceinline__ float cost_val(float x /*cls logit*/, float lo /*logsig(obj)*/,
                                          float sn /*s_neg*/, float v /*masked iou*/,
                                          bool ac, bool f0, bool valid) {
    float lq = 0.5f * (logsig_fast(x) + lo);
    float q = fminf(fmaxf(__expf(lq), 1e-7f), 1.f - 1e-7f);
    float cst = -__logf(q) + __logf(1.f - q) - sn;
    cst -= 3.0f * __logf(v + 1e-8f);
    cst += 100000.0f * (ac ? 0.f : 1.f);
    cst += 1000000000.0f * ((!f0 || !valid) ? 1.f : 0.f);
    return cst;
}

// ---------------- K1: geometry + fg0 compaction (runs FIRST; compacts pred box) ----
__global__ void k_geom(const float* __restrict__ labels, const float* __restrict__ xs,
                       const float* __restrict__ ys, const float* __restrict__ ss,
                       const float* __restrict__ pred,
                       unsigned long long* __restrict__ amask,
                       int* __restrict__ clist, unsigned long long* __restrict__ camask,
                       float4* __restrict__ cpbox, int* __restrict__ ccnt) {
    int b = blockIdx.y;
    int a = blockIdx.x * blockDim.x + threadIdx.x;
    __shared__ float lab[GG * 5];
    __shared__ int lv[GG];
    for (int t = threadIdx.x; t < GG * 5; t += blockDim.x) lab[t] = labels[b * GG * 5 + t];
    __syncthreads();
    if (threadIdx.x < GG) {
        const float* r = lab + threadIdx.x * 5;
        lv[threadIdx.x] = ((r[0] + r[1] + r[2] + r[3] + r[4]) > 0.f) ? 1 : 0;
    }
    __syncthreads();
    if (a >= AA) return;
    float s = ss[a];
    float xc = (xs[a] + 0.5f) * s;
    float yc = (ys[a] + 0.5f) * s;
    unsigned long long m = 0;
    int any = 0;
    for (int g = 0; g < GG; g++) {
        if (!lv[g]) continue;
        const float* r = lab + g * 5;
        float gx = r[1], gy = r[2], gw = r[3], gh = r[4];
        float d1 = xc - (gx - gw * 0.5f);
        float d2 = (gx + gw * 0.5f) - xc;
        float d3 = yc - (gy - gh * 0.5f);
        float d4 = (gy + gh * 0.5f) - yc;
        bool ib = fminf(fminf(d1, d2), fminf(d3, d4)) > 0.f;
        float cr = 2.5f * s;
        float e1 = xc - (gx - cr);
        float e2 = (gx + cr) - xc;
        float e3 = yc - (gy - cr);
        float e4 = (gy + cr) - yc;
        bool ic = fminf(fminf(e1, e2), fminf(e3, e4)) > 0.f;
        if (ib || ic) any = 1;
        if (ib && ic) m |= 1ull << g;
    }
    if (any) m |= 1ull << FGBIT;
    amask[b * AA + a] = m;
    int lane = threadIdx.x & 63;
    unsigned long long act = __ballot(m != 0);
    if (act) {
        int leader = __ffsll(act) - 1;
        int base = 0;
        if (lane == leader) base = atomicAdd(&ccnt[b], __popcll(act));
        base = __shfl(base, leader);
        if (m != 0) {
            int off = __popcll(act & ((1ull << lane) - 1ull));
            int pos = b * AA + base + off;
            clist[pos] = a;
            camask[pos] = m;
            const float* p = pred + (size_t)(b * AA + a) * PCH;
            cpbox[pos] = make_float4(p[0], p[1], p[2], p[3]);
        }
    }
}

// ---------------- K2: per-anchor precompute, fg0-COMPACTED anchors only ----------
__global__ __launch_bounds__(256)
void k_pre_fg(const float* __restrict__ obj, const float* __restrict__ cls,
              const int* __restrict__ clist, const int* __restrict__ ccnt,
              float2* __restrict__ clsn, float2* __restrict__ lsn,
              float* __restrict__ sps) {
    int b = blockIdx.y;
    int cnt = ccnt[b];
    int t = blockIdx.x * blockDim.x + threadIdx.x;
    int p = t >> 2;                    // compacted position
    int sub = t & 3;
    if (p >= cnt) return;
    int pos = b * AA + p;
    int a = clist[pos];
    int ia = b * AA + a;
    float lo = logsig_fast(obj[ia]);
    float K = __expf(0.5f * lo);
    const float4* c4 = (const float4*)(cls + (size_t)ia * CC);
    float smax = 0.f, psp = 1.f, p1 = 1.f, p2 = 1.f;
#pragma unroll
    for (int j = 0; j < 5; j++) {
        float4 v = c4[sub + 4 * j];
        float xs4[4] = {v.x, v.y, v.z, v.w};
        float pg = 1.f;
#pragma unroll
        for (int u = 0; u < 4; u++) {
            float x = xs4[u];
            float th = __expf(-0.5f * fabsf(x));
            float t2 = th * th;
            smax += fmaxf(x, 0.f);
            psp *= (1.f + t2);
            float qq = K * (x < 0.f ? th : 1.f) * rsqrtf(1.f + t2);
            qq = fminf(fmaxf(qq, 1e-7f), 1.f - 1e-7f);
            pg *= (1.f - qq);
        }
        if (j < 2) p1 *= pg; else p2 *= pg;
    }
    float sp = smax + __logf(psp);
    float sn = __logf(p1) + __logf(p2);
    sp += __shfl_xor(sp, 1); sn += __shfl_xor(sn, 1);
    sp += __shfl_xor(sp, 2); sn += __shfl_xor(sn, 2);
    if (sub == 0) {
        clsn[pos] = make_float2(lo, sn);
        lsn[ia] = make_float2(lo, sn);
        sps[ia] = sp;
    }
}

// ---------------- K3: fused cost+assign; INTERLEAVED extraction chains ----------
__global__ __launch_bounds__(256, 4)
void k_assign(const float* __restrict__ pred, const float2* __restrict__ lsn,
              const float* __restrict__ cls,
              const unsigned long long* __restrict__ amask,
              const float* __restrict__ labels,
              const int* __restrict__ clist, const unsigned long long* __restrict__ camask,
              const float4* __restrict__ cpbox, const float2* __restrict__ clsn,
              const int* __restrict__ ccnt,
              unsigned long long* __restrict__ mmask) {
    int w = blockIdx.x;
    int b = w / GG, g = w % GG;
    const float* r = labels + (size_t)w * 5;
    float gcls = r[0], gx = r[1], gy = r[2], gw = r[3], gh = r[4];
    if (!((gcls + gx + gy + gw + gh) > 0.f)) return;  // invalid gt (uniform exit)
    int gtc = (int)gcls;
    int tid = threadIdx.x;
    int lane = tid & 63;
    int wv = tid >> 6;               // 4 waves
    int cnt = ccnt[b];

    // per-lane lists
    float ivl[10];                   // lane top-10 iou, descending (init 0)
    float cvl[10];                   // lane top-10 cost, ascending lex
    int   cil[10];
#pragma unroll
    for (int t = 0; t < 10; t++) { ivl[t] = 0.f; cvl[t] = SENTC; cil[t] = SENTI; }
    int nlc = 0;                     // lane-local and_ctr count

    for (int i0 = wv * 64 + lane; i0 < cnt; i0 += 256) {
        int pos = b * AA + i0;
        unsigned long long am = camask[pos];  // sequential
        float4 pb = cpbox[pos];               // sequential
        bool ac = (am >> g) & 1ull;
        nlc += ac ? 1 : 0;
        float v = pair_iou(pb.x, pb.y, pb.z, pb.w, gx, gy, gw, gh);  // f0 always set
        if (v > ivl[9]) {
            float mv = v;
#pragma unroll
            for (int t = 0; t < 10; t++)
                if (mv > ivl[t]) { float tmp = ivl[t]; ivl[t] = mv; mv = tmp; }
        }
        if (ac) {
            int a = clist[pos];
            float2 ls = clsn[pos];
            float c = cost_val(cls[((size_t)b * AA + a) * CC + gtc], ls.x, ls.y, v,
                               true, true, true);
            int id = a;
            if (c < cvl[9] || (c == cvl[9] && id < cil[9])) {
#pragma unroll
                for (int t = 0; t < 10; t++) {
                    bool sw = (c < cvl[t]) || (c == cvl[t] && id < cil[t]);
                    if (sw) {
                        float tf = cvl[t]; cvl[t] = c; c = tf;
                        int ti = cil[t]; cil[t] = id; id = ti;
                    }
                }
            }
        }
    }

    __shared__ float IV[4][10];
    __shared__ float CV[4][10];
    __shared__ int CI[4][10];
    __shared__ int NAC[4];
    __shared__ int s_k, s_n0;
    __shared__ int sel[10];

    // wave and_ctr count: butterfly sum
    {
        int s = nlc;
#pragma unroll
        for (int off = 1; off < 64; off <<= 1) s += __shfl_xor(s, off);
        if (lane == 0) NAC[wv] = s;
    }

    // ---- INTERLEAVED wave top-10 extraction: iou chain + cost chain per round ----
    // (independent register sets -> 2x ILP on the shfl dependency chains; each
    //  chain's compare/pop sequence identical to the sequential version)
    for (int rr = 0; rr < 10; rr++) {
        float bv = ivl[0];
        int bl = lane;
        float bc = cvl[0];
        int bi = cil[0];
        int cl = lane;
#pragma unroll
        for (int off = 1; off < 64; off <<= 1) {
            float ov = __shfl_xor(bv, off);
            int ol = __shfl_xor(bl, off);
            float oc = __shfl_xor(bc, off);
            int oi = __shfl_xor(bi, off);
            int ocl = __shfl_xor(cl, off);
            if (ov > bv || (ov == bv && ol < bl)) { bv = ov; bl = ol; }
            bool tk = (oc < bc) || (oc == bc && (oi < bi || (oi == bi && ocl < cl)));
            if (tk) { bc = oc; bi = oi; cl = ocl; }
        }
        if (lane == 0) { IV[wv][rr] = bv; CV[wv][rr] = bc; CI[wv][rr] = bi; }
        if (lane == bl) {
#pragma unroll
            for (int t = 0; t < 9; t++) ivl[t] = ivl[t + 1];
            ivl[9] = 0.f;
        }
        if (lane == cl) {
#pragma unroll
            for (int t = 0; t < 9; t++) { cvl[t] = cvl[t + 1]; cil[t] = cil[t + 1]; }
            cvl[9] = SENTC; cil[9] = SENTI;
        }
    }
    __syncthreads();

    if (tid == 0) {
        int h[4] = {0, 0, 0, 0};
        float ssum = 0.f;
        for (int j = 0; j < 10; j++) {      // 4-way descending merge of iou lists
            float bv = -1.f; int bc = 0;
#pragma unroll
            for (int c2 = 0; c2 < 4; c2++)
                if (h[c2] < 10 && IV[c2][h[c2]] > bv) { bv = IV[c2][h[c2]]; bc = c2; }
            ssum += bv;
            h[bc]++;
        }
        int k = (int)ssum;
        if (k < 1) k = 1;
        s_k = k;
        s_n0 = NAC[0] + NAC[1] + NAC[2] + NAC[3];
    }
    __syncthreads();
    int k = s_k;

    if (s_n0 < k) {
        // ---- rare fallback: full-cost rescan over ALL anchors ----
#pragma unroll
        for (int t = 0; t < 10; t++) { cvl[t] = SENTC; cil[t] = SENTI; }
        const int chunk = AA / 4;
        int abase = wv * chunk, aend = abase + chunk;
        for (int a0 = abase; a0 < aend; a0 += 64) {
            int a = a0 + lane;
            bool inr = a < aend;
            int ia = b * AA + (inr ? a : (aend - 1));
            unsigned long long am = amask[ia];
            bool f0 = inr && ((am >> FGBIT) & 1ull);
            bool ac = inr && ((am >> g) & 1ull);
            float v = 0.f;
            if (f0) {
                const float* p = pred + (size_t)ia * PCH;
                v = pair_iou(p[0], p[1], p[2], p[3], gx, gy, gw, gh);
            }
            float c = SENTC; int id = SENTI;
            if (inr) {
                float x = cls[(size_t)ia * CC + gtc];
                float2 ls = lsn[ia];
                c = cost_val(x, ls.x, ls.y, v, ac, f0, true);
                id = a;
            }
            if (c < cvl[9] || (c == cvl[9] && id < cil[9])) {
#pragma unroll
                for (int t = 0; t < 10; t++) {
                    bool sw = (c < cvl[t]) || (c == cvl[t] && id < cil[t]);
                    if (sw) {
                        float tf = cvl[t]; cvl[t] = c; c = tf;
                        int ti = cil[t]; cil[t] = id; id = ti;
                    }
                }
            }
        }
        for (int rr = 0; rr < 10; rr++) {
            float bc = cvl[0];
            int bi = cil[0];
            int bl = lane;
#pragma unroll
            for (int off = 1; off < 64; off <<= 1) {
                float oc = __shfl_xor(bc, off);
                int oi = __shfl_xor(bi, off);
                int ol = __shfl_xor(bl, off);
                bool tk = (oc < bc) || (oc == bc && (oi < bi || (oi == bi && ol < bl)));
                if (tk) { bc = oc; bi = oi; bl = ol; }
            }
            if (lane == 0) { CV[wv][rr] = bc; CI[wv][rr] = bi; }
            if (lane == bl) {
#pragma unroll
                for (int t = 0; t < 9; t++) { cvl[t] = cvl[t + 1]; cil[t] = cil[t + 1]; }
                cvl[9] = SENTC; cil[9] = SENTI;
            }
        }
        __syncthreads();
    }

    if (tid == 0) {
        int h[4] = {0, 0, 0, 0};
        for (int j = 0; j < k; j++) {       // 4-way lex-ascending merge, take k
            float bv = SENTC; int bix = SENTI; int bc = 0;
#pragma unroll
            for (int c2 = 0; c2 < 4; c2++) {
                if (h[c2] < 10) {
                    float av = CV[c2][h[c2]]; int ax = CI[c2][h[c2]];
                    if (av < bv || (av == bv && ax < bix)) { bv = av; bix = ax; bc = c2; }
                }
            }
            sel[j] = bix;
            h[bc]++;
        }
    }
    __syncthreads();
    if (tid < k) {
        atomicOr(&mmask[(size_t)b * AA + sel[tid]], 1ull << g);
    }
}

// ---------------- K4: loss partials; labels in LDS; box from pred (masked) ----
__global__ void k_loss(const float* __restrict__ pred, const float* __restrict__ obj,
                       const float* __restrict__ cls, const float* __restrict__ labels,
                       const float2* __restrict__ lsn,
                       const unsigned long long* __restrict__ amask,
                       const unsigned long long* __restrict__ mmask,
                       const float* __restrict__ sps, float* __restrict__ partial) {
    int i = blockIdx.x * blockDim.x + threadIdx.x;
    int i_first = blockIdx.x * blockDim.x;
    int i_last = min(i_first + (int)blockDim.x - 1, BB * AA - 1);
    int b0 = i_first / AA, b1 = i_last / AA;
    __shared__ float lab[2][GG * 5];
    for (int t = threadIdx.x; t < GG * 5; t += blockDim.x) {
        lab[0][t] = labels[(size_t)b0 * GG * 5 + t];
        lab[1][t] = labels[(size_t)b1 * GG * 5 + t];
    }
    __syncthreads();

    float li = 0.f, lo = 0.f, lc = 0.f, nf = 0.f;
    if (i < BB * AA) {
        int b = i / AA, a = i % AA;
        const float* lb = lab[(b == b0) ? 0 : 1];
        unsigned long long m = mmask[i];
        int cnt = __popcll(m);
        bool fg = (m != 0);
        int mg = 0;
        float4 pb = make_float4(0.f, 0.f, 0.f, 0.f);
        if (fg) {
            const float* p = pred + (size_t)i * PCH;
            pb = make_float4(p[0], p[1], p[2], p[3]);
        }
        unsigned long long am = amask[i];
        bool f0 = (am >> FGBIT) & 1ull;
        if (cnt > 1) {
            float2 ls = lsn[i];
            float bv = 3.4e38f;
            for (int g = 0; g < GG; g++) {
                const float* r = lb + g * 5;
                float gcls = r[0], gx = r[1], gy = r[2], gw = r[3], gh = r[4];
                bool valid = (gcls + gx + gy + gw + gh) > 0.f;
                int gtc = (int)gcls;
                float raw = pair_iou(pb.x, pb.y, pb.z, pb.w, gx, gy, gw, gh);
                float v = raw * (f0 ? 1.f : 0.f) * (valid ? 1.f : 0.f);
                float x = cls[(size_t)i * CC + gtc];
                bool ac = (am >> g) & 1ull;
                float cst = cost_val(x, ls.x, ls.y, v, ac, f0, valid);
                if (cst < bv) { bv = cst; mg = g; }
            }
        } else if (cnt == 1) {
            mg = __ffsll((unsigned long long)m) - 1;
        }
        float o = obj[i];
        lo = softplusf(o) - (fg ? o : 0.f);
        if (fg) {
            const float* r = lb + mg * 5;
            float gcls = r[0], gx = r[1], gy = r[2], gw = r[3], gh = r[4];
            bool valid = (gcls + gx + gy + gw + gh) > 0.f;
            int gtc = (int)gcls;
            float piou = pair_iou(pb.x, pb.y, pb.z, pb.w, gx, gy, gw, gh)
                         * (f0 ? 1.f : 0.f) * (valid ? 1.f : 0.f);
            float tlx = fmaxf(pb.x - pb.z * 0.5f, gx - gw * 0.5f);
            float tly = fmaxf(pb.y - pb.w * 0.5f, gy - gh * 0.5f);
            float brx = fminf(pb.x + pb.z * 0.5f, gx + gw * 0.5f);
            float bry = fminf(pb.y + pb.w * 0.5f, gy + gh * 0.5f);
            float en = (tlx < brx && tly < bry) ? 1.f : 0.f;
            float ai = (brx - tlx) * (bry - tly) * en;
            float u = pb.z * pb.w + gw * gh - ai;
            float v2 = ai / (u + 1e-16f);
            li = 1.f - v2 * v2;
            lc = sps[i] - cls[(size_t)i * CC + gtc] * piou;
            nf = 1.f;
        }
    }
    for (int off = 32; off; off >>= 1) {
        li += __shfl_down(li, off);
        lo += __shfl_down(lo, off);
        lc += __shfl_down(lc, off);
        nf += __shfl_down(nf, off);
    }
    __shared__ float red[4][4];
    int wid = threadIdx.x >> 6;
    if ((threadIdx.x & 63) == 0) {
        red[wid][0] = li; red[wid][1] = lo; red[wid][2] = lc; red[wid][3] = nf;
    }
    __syncthreads();
    if (threadIdx.x == 0) {
        float s0 = 0.f, s1 = 0.f, s2 = 0.f, s3 = 0.f;
#pragma unroll
        for (int t = 0; t < 4; t++) {
            s0 += red[t][0]; s1 += red[t][1]; s2 += red[t][2]; s3 += red[t][3];
        }
        ((float4*)partial)[blockIdx.x] = make_float4(s0, s1, s2, s3);
    }
}

// ---------------- K5: reduce partials, finalize ----------------
__global__ void k_final(const float* __restrict__ partial, float* __restrict__ out) {
    int tid = threadIdx.x;
    float s0 = 0.f, s1 = 0.f, s2 = 0.f, s3 = 0.f;
    const float4* pb = (const float4*)partial;
    for (int i = tid; i < NLB; i += 256) {
        float4 v = pb[i];
        s0 += v.x; s1 += v.y; s2 += v.z; s3 += v.w;
    }
    for (int off = 32; off; off >>= 1) {
        s0 += __shfl_down(s0, off);
        s1 += __shfl_down(s1, off);
        s2 += __shfl_down(s2, off);
        s3 += __shfl_down(s3, off);
    }
    __shared__ float red[4][4];
    int wid = tid >> 6;
    if ((tid & 63) == 0) {
        red[wid][0] = s0; red[wid][1] = s1; red[wid][2] = s2; red[wid][3] = s3;
    }
    __syncthreads();
    if (tid == 0) {
        float li = 0.f, lo = 0.f, lc = 0.f, nf = 0.f;
#pragma unroll
        for (int t = 0; t < 4; t++) {
            li += red[t][0]; lo += red[t][1]; lc += red[t][2]; nf += red[t][3];
        }
        nf = fmaxf(nf, 1.f);
        out[0] = (5.f * li + lo + lc) / nf;
    }
}

extern "C" void kernel_launch(void* const* d_in, const int* in_sizes, int n_in,
                              void* d_out, int out_size, void* d_ws, size_t ws_size,
                              hipStream_t stream) {
    const float* pred = (const float*)d_in[0];   // (B,A,85)
    const float* obj  = (const float*)d_in[1];   // (B,A,1)
    const float* cls  = (const float*)d_in[2];   // (B,A,80)
    const float* lab  = (const float*)d_in[3];   // (B,G,5)
    const float* xs   = (const float*)d_in[4];   // (A,)
    const float* ys   = (const float*)d_in[5];   // (A,)
    const float* ss   = (const float*)d_in[6];   // (A,)
    float* out = (float*)d_out;

    const size_t BA = (size_t)BB * AA;

    float4* cpbox = (float4*)d_ws;                 // BA f32x4 (compacted)
    float2* lsn   = (float2*)(cpbox + BA);         // BA f32x2 (scattered, fg0 only)
    float2* clsn  = lsn + BA;                      // BA f32x2 (compacted)
    unsigned long long* amask  = (unsigned long long*)(clsn + BA);  // BA u64
    unsigned long long* camask = amask + BA;       // BA u64 (compacted)
    unsigned long long* mmask  = camask + BA;      // BA u64
    float* sps = (float*)(mmask + BA);             // BA f32 (scattered, fg0 only)
    float* partial = sps + BA;                     // NLB*4 f32
    int* clist = (int*)(partial + (size_t)NLB * 4); // BA i32
    int* ccnt  = clist + BA;                        // BB i32

    hipMemsetAsync(mmask, 0, BA * sizeof(unsigned long long), stream);
    hipMemsetAsync(ccnt, 0, BB * sizeof(int), stream);

    dim3 blk(256);
    // K1: geometry + compaction
    k_geom<<<dim3((AA + 255) / 256, BB), blk, 0, stream>>>(lab, xs, ys, ss, pred,
                                                           amask, clist, camask, cpbox,
                                                           ccnt);
    // K2: precompute only for compacted fg0 anchors
    k_pre_fg<<<dim3((AA * 4 + 255) / 256, BB), blk, 0, stream>>>(obj, cls, clist, ccnt,
                                                                 clsn, lsn, sps);
    // K3: fused cost+assign, interleaved extraction chains
    k_assign<<<dim3(BB * GG), blk, 0, stream>>>(pred, lsn, cls, amask, lab,
                                                clist, camask, cpbox, clsn, ccnt, mmask);
    // K4: loss partials
    k_loss<<<dim3(NLB), blk, 0, stream>>>(pred, obj, cls, lab, lsn, amask,
                                          mmask, sps, partial);
    // K5
    k_final<<<1, blk, 0, stream>>>(partial, out);
}

// Round 25
// 142.653 us; speedup vs baseline: 1.0872x; 1.0162x over previous
//
#include <hip/hip_runtime.h>
#include <cstdint>
#include <cstddef>

#define BB 32
#define GG 50
#define CC 80
#define AA 8400
#define PCH (5 + CC)   // pred_output channels = 85
#define NLB ((BB * AA + 255) / 256)   // k_loss blocks = 1050
#define FGBIT 63       // fg0 folded into amask bit 63 (g uses bits 0..49)
#define SENTC 3.3e38f  // cost sentinel (> any real cost)
#define SENTI 0x7fffffff

__device__ __forceinline__ float logsig_fast(float x) {
    float e = __expf(-fabsf(x));
    return fminf(x, 0.f) - __logf(1.f + e);
}
__device__ __forceinline__ float softplusf(float x) {
    return fmaxf(x, 0.f) + log1pf(expf(-fabsf(x)));
}

// ---- shared value functions (MUST be identical everywhere) ----
__device__ __forceinline__ float pair_iou(float px, float py, float pw, float ph,
                                          float gx, float gy, float gw, float gh) {
    float tlx = fmaxf(gx - gw * 0.5f, px - pw * 0.5f);
    float tly = fmaxf(gy - gh * 0.5f, py - ph * 0.5f);
    float brx = fminf(gx + gw * 0.5f, px + pw * 0.5f);
    float bry = fminf(gy + gh * 0.5f, py + ph * 0.5f);
    float en = (tlx < brx && tly < bry) ? 1.f : 0.f;
    float ai = (brx - tlx) * (bry - tly) * en;
    return ai / (gw * gh + pw * ph - ai + 1e-16f);
}
__device__ __forceinline__ float cost_val(float x /*cls logit*/, float lo /*logsig(obj)*/,
                                          float sn /*s_neg*/, float v /*masked iou*/,
                                          bool ac, bool f0, bool valid) {
    float lq = 0.5f * (logsig_fast(x) + lo);
    float q = fminf(fmaxf(__expf(lq), 1e-7f), 1.f - 1e-7f);
    float cst = -__logf(q) + __logf(1.f - q) - sn;
    cst -= 3.0f * __logf(v + 1e-8f);
    cst += 100000.0f * (ac ? 0.f : 1.f);
    cst += 1000000000.0f * ((!f0 || !valid) ? 1.f : 0.f);
    return cst;
}

// ---------------- K0: zero the per-image compaction counters ----------------
__global__ void k_zero(int* __restrict__ ccnt) {
    if (threadIdx.x < BB) ccnt[threadIdx.x] = 0;
}

// ---------------- K1: geometry + fg0 compaction; also zeroes mmask ----------------
__global__ void k_geom(const float* __restrict__ labels, const float* __restrict__ xs,
                       const float* __restrict__ ys, const float* __restrict__ ss,
                       const float* __restrict__ pred,
                       unsigned long long* __restrict__ amask,
                       int* __restrict__ clist, unsigned long long* __restrict__ camask,
                       float4* __restrict__ cpbox, int* __restrict__ ccnt,
                       unsigned long long* __restrict__ mmask) {
    int b = blockIdx.y;
    int a = blockIdx.x * blockDim.x + threadIdx.x;
    __shared__ float lab[GG * 5];
    __shared__ int lv[GG];
    for (int t = threadIdx.x; t < GG * 5; t += blockDim.x) lab[t] = labels[b * GG * 5 + t];
    __syncthreads();
    if (threadIdx.x < GG) {
        const float* r = lab + threadIdx.x * 5;
        lv[threadIdx.x] = ((r[0] + r[1] + r[2] + r[3] + r[4]) > 0.f) ? 1 : 0;
    }
    __syncthreads();
    if (a >= AA) return;
    mmask[b * AA + a] = 0ull;          // zero atomicOr destination (pre-k_assign)
    float s = ss[a];
    float xc = (xs[a] + 0.5f) * s;
    float yc = (ys[a] + 0.5f) * s;
    unsigned long long m = 0;
    int any = 0;
    for (int g = 0; g < GG; g++) {
        if (!lv[g]) continue;
        const float* r = lab + g * 5;
        float gx = r[1], gy = r[2], gw = r[3], gh = r[4];
        float d1 = xc - (gx - gw * 0.5f);
        float d2 = (gx + gw * 0.5f) - xc;
        float d3 = yc - (gy - gh * 0.5f);
        float d4 = (gy + gh * 0.5f) - yc;
        bool ib = fminf(fminf(d1, d2), fminf(d3, d4)) > 0.f;
        float cr = 2.5f * s;
        float e1 = xc - (gx - cr);
        float e2 = (gx + cr) - xc;
        float e3 = yc - (gy - cr);
        float e4 = (gy + cr) - yc;
        bool ic = fminf(fminf(e1, e2), fminf(e3, e4)) > 0.f;
        if (ib || ic) any = 1;
        if (ib && ic) m |= 1ull << g;
    }
    if (any) m |= 1ull << FGBIT;
    amask[b * AA + a] = m;
    int lane = threadIdx.x & 63;
    unsigned long long act = __ballot(m != 0);
    if (act) {
        int leader = __ffsll(act) - 1;
        int base = 0;
        if (lane == leader) base = atomicAdd(&ccnt[b], __popcll(act));
        base = __shfl(base, leader);
        if (m != 0) {
            int off = __popcll(act & ((1ull << lane) - 1ull));
            int pos = b * AA + base + off;
            clist[pos] = a;
            camask[pos] = m;
            const float* p = pred + (size_t)(b * AA + a) * PCH;
            cpbox[pos] = make_float4(p[0], p[1], p[2], p[3]);
        }
    }
}

// ---------------- K2: per-anchor precompute, fg0-COMPACTED anchors only ----------
__global__ __launch_bounds__(256)
void k_pre_fg(const float* __restrict__ obj, const float* __restrict__ cls,
              const int* __restrict__ clist, const int* __restrict__ ccnt,
              float2* __restrict__ clsn, float2* __restrict__ lsn,
              float* __restrict__ sps) {
    int b = blockIdx.y;
    int cnt = ccnt[b];
    int t = blockIdx.x * blockDim.x + threadIdx.x;
    int p = t >> 2;                    // compacted position
    int sub = t & 3;
    if (p >= cnt) return;
    int pos = b * AA + p;
    int a = clist[pos];
    int ia = b * AA + a;
    float lo = logsig_fast(obj[ia]);
    float K = __expf(0.5f * lo);
    const float4* c4 = (const float4*)(cls + (size_t)ia * CC);
    float smax = 0.f, psp = 1.f, p1 = 1.f, p2 = 1.f;
#pragma unroll
    for (int j = 0; j < 5; j++) {
        float4 v = c4[sub + 4 * j];
        float xs4[4] = {v.x, v.y, v.z, v.w};
        float pg = 1.f;
#pragma unroll
        for (int u = 0; u < 4; u++) {
            float x = xs4[u];
            float th = __expf(-0.5f * fabsf(x));
            float t2 = th * th;
            smax += fmaxf(x, 0.f);
            psp *= (1.f + t2);
            float qq = K * (x < 0.f ? th : 1.f) * rsqrtf(1.f + t2);
            qq = fminf(fmaxf(qq, 1e-7f), 1.f - 1e-7f);
            pg *= (1.f - qq);
        }
        if (j < 2) p1 *= pg; else p2 *= pg;
    }
    float sp = smax + __logf(psp);
    float sn = __logf(p1) + __logf(p2);
    sp += __shfl_xor(sp, 1); sn += __shfl_xor(sn, 1);
    sp += __shfl_xor(sp, 2); sn += __shfl_xor(sn, 2);
    if (sub == 0) {
        clsn[pos] = make_float2(lo, sn);
        lsn[ia] = make_float2(lo, sn);
        sps[ia] = sp;
    }
}

// ---------------- K3: fused cost+assign; INTERLEAVED extraction chains ----------
__global__ __launch_bounds__(256, 4)
void k_assign(const float* __restrict__ pred, const float2* __restrict__ lsn,
              const float* __restrict__ cls,
              const unsigned long long* __restrict__ amask,
              const float* __restrict__ labels,
              const int* __restrict__ clist, const unsigned long long* __restrict__ camask,
              const float4* __restrict__ cpbox, const float2* __restrict__ clsn,
              const int* __restrict__ ccnt,
              unsigned long long* __restrict__ mmask) {
    int w = blockIdx.x;
    int b = w / GG, g = w % GG;
    const float* r = labels + (size_t)w * 5;
    float gcls = r[0], gx = r[1], gy = r[2], gw = r[3], gh = r[4];
    if (!((gcls + gx + gy + gw + gh) > 0.f)) return;  // invalid gt (uniform exit)
    int gtc = (int)gcls;
    int tid = threadIdx.x;
    int lane = tid & 63;
    int wv = tid >> 6;               // 4 waves
    int cnt = ccnt[b];

    // per-lane lists
    float ivl[10];                   // lane top-10 iou, descending (init 0)
    float cvl[10];                   // lane top-10 cost, ascending lex
    int   cil[10];
#pragma unroll
    for (int t = 0; t < 10; t++) { ivl[t] = 0.f; cvl[t] = SENTC; cil[t] = SENTI; }
    int nlc = 0;                     // lane-local and_ctr count

    for (int i0 = wv * 64 + lane; i0 < cnt; i0 += 256) {
        int pos = b * AA + i0;
        unsigned long long am = camask[pos];  // sequential
        float4 pb = cpbox[pos];               // sequential
        bool ac = (am >> g) & 1ull;
        nlc += ac ? 1 : 0;
        float v = pair_iou(pb.x, pb.y, pb.z, pb.w, gx, gy, gw, gh);  // f0 always set
        if (v > ivl[9]) {
            float mv = v;
#pragma unroll
            for (int t = 0; t < 10; t++)
                if (mv > ivl[t]) { float tmp = ivl[t]; ivl[t] = mv; mv = tmp; }
        }
        if (ac) {
            int a = clist[pos];
            float2 ls = clsn[pos];
            float c = cost_val(cls[((size_t)b * AA + a) * CC + gtc], ls.x, ls.y, v,
                               true, true, true);
            int id = a;
            if (c < cvl[9] || (c == cvl[9] && id < cil[9])) {
#pragma unroll
                for (int t = 0; t < 10; t++) {
                    bool sw = (c < cvl[t]) || (c == cvl[t] && id < cil[t]);
                    if (sw) {
                        float tf = cvl[t]; cvl[t] = c; c = tf;
                        int ti = cil[t]; cil[t] = id; id = ti;
                    }
                }
            }
        }
    }

    __shared__ float IV[4][10];
    __shared__ float CV[4][10];
    __shared__ int CI[4][10];
    __shared__ int NAC[4];
    __shared__ int s_k, s_n0;
    __shared__ int sel[10];

    // wave and_ctr count: butterfly sum
    {
        int s = nlc;
#pragma unroll
        for (int off = 1; off < 64; off <<= 1) s += __shfl_xor(s, off);
        if (lane == 0) NAC[wv] = s;
    }

    // ---- INTERLEAVED wave top-10 extraction: iou chain + cost chain per round ----
    for (int rr = 0; rr < 10; rr++) {
        float bv = ivl[0];
        int bl = lane;
        float bc = cvl[0];
        int bi = cil[0];
        int cl = lane;
#pragma unroll
        for (int off = 1; off < 64; off <<= 1) {
            float ov = __shfl_xor(bv, off);
            int ol = __shfl_xor(bl, off);
            float oc = __shfl_xor(bc, off);
            int oi = __shfl_xor(bi, off);
            int ocl = __shfl_xor(cl, off);
            if (ov > bv || (ov == bv && ol < bl)) { bv = ov; bl = ol; }
            bool tk = (oc < bc) || (oc == bc && (oi < bi || (oi == bi && ocl < cl)));
            if (tk) { bc = oc; bi = oi; cl = ocl; }
        }
        if (lane == 0) { IV[wv][rr] = bv; CV[wv][rr] = bc; CI[wv][rr] = bi; }
        if (lane == bl) {
#pragma unroll
            for (int t = 0; t < 9; t++) ivl[t] = ivl[t + 1];
            ivl[9] = 0.f;
        }
        if (lane == cl) {
#pragma unroll
            for (int t = 0; t < 9; t++) { cvl[t] = cvl[t + 1]; cil[t] = cil[t + 1]; }
            cvl[9] = SENTC; cil[9] = SENTI;
        }
    }
    __syncthreads();

    if (tid == 0) {
        int h[4] = {0, 0, 0, 0};
        float ssum = 0.f;
        for (int j = 0; j < 10; j++) {      // 4-way descending merge of iou lists
            float bv = -1.f; int bc = 0;
#pragma unroll
            for (int c2 = 0; c2 < 4; c2++)
                if (h[c2] < 10 && IV[c2][h[c2]] > bv) { bv = IV[c2][h[c2]]; bc = c2; }
            ssum += bv;
            h[bc]++;
        }
        int k = (int)ssum;
        if (k < 1) k = 1;
        s_k = k;
        s_n0 = NAC[0] + NAC[1] + NAC[2] + NAC[3];
    }
    __syncthreads();
    int k = s_k;

    if (s_n0 < k) {
        // ---- rare fallback: full-cost rescan over ALL anchors ----
#pragma unroll
        for (int t = 0; t < 10; t++) { cvl[t] = SENTC; cil[t] = SENTI; }
        const int chunk = AA / 4;
        int abase = wv * chunk, aend = abase + chunk;
        for (int a0 = abase; a0 < aend; a0 += 64) {
            int a = a0 + lane;
            bool inr = a < aend;
            int ia = b * AA + (inr ? a : (aend - 1));
            unsigned long long am = amask[ia];
            bool f0 = inr && ((am >> FGBIT) & 1ull);
            bool ac = inr && ((am >> g) & 1ull);
            float v = 0.f;
            if (f0) {
                const float* p = pred + (size_t)ia * PCH;
                v = pair_iou(p[0], p[1], p[2], p[3], gx, gy, gw, gh);
            }
            float c = SENTC; int id = SENTI;
            if (inr) {
                float x = cls[(size_t)ia * CC + gtc];
                float2 ls = lsn[ia];
                c = cost_val(x, ls.x, ls.y, v, ac, f0, true);
                id = a;
            }
            if (c < cvl[9] || (c == cvl[9] && id < cil[9])) {
#pragma unroll
                for (int t = 0; t < 10; t++) {
                    bool sw = (c < cvl[t]) || (c == cvl[t] && id < cil[t]);
                    if (sw) {
                        float tf = cvl[t]; cvl[t] = c; c = tf;
                        int ti = cil[t]; cil[t] = id; id = ti;
                    }
                }
            }
        }
        for (int rr = 0; rr < 10; rr++) {
            float bc = cvl[0];
            int bi = cil[0];
            int bl = lane;
#pragma unroll
            for (int off = 1; off < 64; off <<= 1) {
                float oc = __shfl_xor(bc, off);
                int oi = __shfl_xor(bi, off);
                int ol = __shfl_xor(bl, off);
                bool tk = (oc < bc) || (oc == bc && (oi < bi || (oi == bi && ol < bl)));
                if (tk) { bc = oc; bi = oi; bl = ol; }
            }
            if (lane == 0) { CV[wv][rr] = bc; CI[wv][rr] = bi; }
            if (lane == bl) {
#pragma unroll
                for (int t = 0; t < 9; t++) { cvl[t] = cvl[t + 1]; cil[t] = cil[t + 1]; }
                cvl[9] = SENTC; cil[9] = SENTI;
            }
        }
        __syncthreads();
    }

    if (tid == 0) {
        int h[4] = {0, 0, 0, 0};
        for (int j = 0; j < k; j++) {       // 4-way lex-ascending merge, take k
            float bv = SENTC; int bix = SENTI; int bc = 0;
#pragma unroll
            for (int c2 = 0; c2 < 4; c2++) {
                if (h[c2] < 10) {
                    float av = CV[c2][h[c2]]; int ax = CI[c2][h[c2]];
                    if (av < bv || (av == bv && ax < bix)) { bv = av; bix = ax; bc = c2; }
                }
            }
            sel[j] = bix;
            h[bc]++;
        }
    }
    __syncthreads();
    if (tid < k) {
        atomicOr(&mmask[(size_t)b * AA + sel[tid]], 1ull << g);
    }
}

// ---------------- K4: loss partials; labels in LDS; box from pred (masked) ----
__global__ void k_loss(const float* __restrict__ pred, const float* __restrict__ obj,
                       const float* __restrict__ cls, const float* __restrict__ labels,
                       const float2* __restrict__ lsn,
                       const unsigned long long* __restrict__ amask,
                       const unsigned long long* __restrict__ mmask,
                       const float* __restrict__ sps, float* __restrict__ partial) {
    int i = blockIdx.x * blockDim.x + threadIdx.x;
    int i_first = blockIdx.x * blockDim.x;
    int i_last = min(i_first + (int)blockDim.x - 1, BB * AA - 1);
    int b0 = i_first / AA, b1 = i_last / AA;
    __shared__ float lab[2][GG * 5];
    for (int t = threadIdx.x; t < GG * 5; t += blockDim.x) {
        lab[0][t] = labels[(size_t)b0 * GG * 5 + t];
        lab[1][t] = labels[(size_t)b1 * GG * 5 + t];
    }
    __syncthreads();

    float li = 0.f, lo = 0.f, lc = 0.f, nf = 0.f;
    if (i < BB * AA) {
        int b = i / AA, a = i % AA;
        const float* lb = lab[(b == b0) ? 0 : 1];
        unsigned long long m = mmask[i];
        int cnt = __popcll(m);
        bool fg = (m != 0);
        int mg = 0;
        float4 pb = make_float4(0.f, 0.f, 0.f, 0.f);
        if (fg) {
            const float* p = pred + (size_t)i * PCH;
            pb = make_float4(p[0], p[1], p[2], p[3]);
        }
        unsigned long long am = amask[i];
        bool f0 = (am >> FGBIT) & 1ull;
        if (cnt > 1) {
            float2 ls = lsn[i];
            float bv = 3.4e38f;
            for (int g = 0; g < GG; g++) {
                const float* r = lb + g * 5;
                float gcls = r[0], gx = r[1], gy = r[2], gw = r[3], gh = r[4];
                bool valid = (gcls + gx + gy + gw + gh) > 0.f;
                int gtc = (int)gcls;
                float raw = pair_iou(pb.x, pb.y, pb.z, pb.w, gx, gy, gw, gh);
                float v = raw * (f0 ? 1.f : 0.f) * (valid ? 1.f : 0.f);
                float x = cls[(size_t)i * CC + gtc];
                bool ac = (am >> g) & 1ull;
                float cst = cost_val(x, ls.x, ls.y, v, ac, f0, valid);
                if (cst < bv) { bv = cst; mg = g; }
            }
        } else if (cnt == 1) {
            mg = __ffsll((unsigned long long)m) - 1;
        }
        float o = obj[i];
        lo = softplusf(o) - (fg ? o : 0.f);
        if (fg) {
            const float* r = lb + mg * 5;
            float gcls = r[0], gx = r[1], gy = r[2], gw = r[3], gh = r[4];
            bool valid = (gcls + gx + gy + gw + gh) > 0.f;
            int gtc = (int)gcls;
            float piou = pair_iou(pb.x, pb.y, pb.z, pb.w, gx, gy, gw, gh)
                         * (f0 ? 1.f : 0.f) * (valid ? 1.f : 0.f);
            float tlx = fmaxf(pb.x - pb.z * 0.5f, gx - gw * 0.5f);
            float tly = fmaxf(pb.y - pb.w * 0.5f, gy - gh * 0.5f);
            float brx = fminf(pb.x + pb.z * 0.5f, gx + gw * 0.5f);
            float bry = fminf(pb.y + pb.w * 0.5f, gy + gh * 0.5f);
            float en = (tlx < brx && tly < bry) ? 1.f : 0.f;
            float ai = (brx - tlx) * (bry - tly) * en;
            float u = pb.z * pb.w + gw * gh - ai;
            float v2 = ai / (u + 1e-16f);
            li = 1.f - v2 * v2;
            lc = sps[i] - cls[(size_t)i * CC + gtc] * piou;
            nf = 1.f;
        }
    }
    for (int off = 32; off; off >>= 1) {
        li += __shfl_down(li, off);
        lo += __shfl_down(lo, off);
        lc += __shfl_down(lc, off);
        nf += __shfl_down(nf, off);
    }
    __shared__ float red[4][4];
    int wid = threadIdx.x >> 6;
    if ((threadIdx.x & 63) == 0) {
        red[wid][0] = li; red[wid][1] = lo; red[wid][2] = lc; red[wid][3] = nf;
    }
    __syncthreads();
    if (threadIdx.x == 0) {
        float s0 = 0.f, s1 = 0.f, s2 = 0.f, s3 = 0.f;
#pragma unroll
        for (int t = 0; t < 4; t++) {
            s0 += red[t][0]; s1 += red[t][1]; s2 += red[t][2]; s3 += red[t][3];
        }
        ((float4*)partial)[blockIdx.x] = make_float4(s0, s1, s2, s3);
    }
}

// ---------------- K5: reduce partials, finalize ----------------
__global__ void k_final(const float* __restrict__ partial, float* __restrict__ out) {
    int tid = threadIdx.x;
    float s0 = 0.f, s1 = 0.f, s2 = 0.f, s3 = 0.f;
    const float4* pb = (const float4*)partial;
    for (int i = tid; i < NLB; i += 256) {
        float4 v = pb[i];
        s0 += v.x; s1 += v.y; s2 += v.z; s3 += v.w;
    }
    for (int off = 32; off; off >>= 1) {
        s0 += __shfl_down(s0, off);
        s1 += __shfl_down(s1, off);
        s2 += __shfl_down(s2, off);
        s3 += __shfl_down(s3, off);
    }
    __shared__ float red[4][4];
    int wid = tid >> 6;
    if ((tid & 63) == 0) {
        red[wid][0] = s0; red[wid][1] = s1; red[wid][2] = s2; red[wid][3] = s3;
    }
    __syncthreads();
    if (tid == 0) {
        float li = 0.f, lo = 0.f, lc = 0.f, nf = 0.f;
#pragma unroll
        for (int t = 0; t < 4; t++) {
            li += red[t][0]; lo += red[t][1]; lc += red[t][2]; nf += red[t][3];
        }
        nf = fmaxf(nf, 1.f);
        out[0] = (5.f * li + lo + lc) / nf;
    }
}

extern "C" void kernel_launch(void* const* d_in, const int* in_sizes, int n_in,
                              void* d_out, int out_size, void* d_ws, size_t ws_size,
                              hipStream_t stream) {
    const float* pred = (const float*)d_in[0];   // (B,A,85)
    const float* obj  = (const float*)d_in[1];   // (B,A,1)
    const float* cls  = (const float*)d_in[2];   // (B,A,80)
    const float* lab  = (const float*)d_in[3];   // (B,G,5)
    const float* xs   = (const float*)d_in[4];   // (A,)
    const float* ys   = (const float*)d_in[5];   // (A,)
    const float* ss   = (const float*)d_in[6];   // (A,)
    float* out = (float*)d_out;

    const size_t BA = (size_t)BB * AA;

    float4* cpbox = (float4*)d_ws;                 // BA f32x4 (compacted)
    float2* lsn   = (float2*)(cpbox + BA);         // BA f32x2 (scattered, fg0 only)
    float2* clsn  = lsn + BA;                      // BA f32x2 (compacted)
    unsigned long long* amask  = (unsigned long long*)(clsn + BA);  // BA u64
    unsigned long long* camask = amask + BA;       // BA u64 (compacted)
    unsigned long long* mmask  = camask + BA;      // BA u64
    float* sps = (float*)(mmask + BA);             // BA f32 (scattered, fg0 only)
    float* partial = sps + BA;                     // NLB*4 f32
    int* clist = (int*)(partial + (size_t)NLB * 4); // BA i32
    int* ccnt  = clist + BA;                        // BB i32

    dim3 blk(256);
    // K0: zero compaction counters (replaces hipMemsetAsync)
    k_zero<<<1, 64, 0, stream>>>(ccnt);
    // K1: geometry + compaction + mmask zeroing
    k_geom<<<dim3((AA + 255) / 256, BB), blk, 0, stream>>>(lab, xs, ys, ss, pred,
                                                           amask, clist, camask, cpbox,
                                                           ccnt, mmask);
    // K2: precompute only for compacted fg0 anchors
    k_pre_fg<<<dim3((AA * 4 + 255) / 256, BB), blk, 0, stream>>>(obj, cls, clist, ccnt,
                                                                 clsn, lsn, sps);
    // K3: fused cost+assign, interleaved extraction chains
    k_assign<<<dim3(BB * GG), blk, 0, stream>>>(pred, lsn, cls, amask, lab,
                                                clist, camask, cpbox, clsn, ccnt, mmask);
    // K4: loss partials
    k_loss<<<dim3(NLB), blk, 0, stream>>>(pred, obj, cls, lab, lsn, amask,
                                          mmask, sps, partial);
    // K5
    k_final<<<1, blk, 0, stream>>>(partial, out);
}